// Round 14
// baseline (130.589 us; speedup 1.0000x reference)
//
#include <hip/hip_runtime.h>
#include <hip/hip_bf16.h>

typedef __attribute__((ext_vector_type(8))) short short8;
typedef __attribute__((ext_vector_type(4))) float float4v;
typedef __attribute__((address_space(3))) unsigned int as3u32;
typedef __attribute__((address_space(1))) unsigned int as1u32;

#define DIN 128
#define SSIZE 1024
#define MLGK 256
#define DOUT 10
#define TM 32   // x-rows per block; ONE wave, 2 row-halves of 16
#define TS 32   // anchors per staged tile
#define NT 32   // anchor tiles

union pk8 { unsigned int w[4]; short8 s8; };

#if __has_builtin(__builtin_amdgcn_sqrtf)
#define fsqrt_fast __builtin_amdgcn_sqrtf
#else
#define fsqrt_fast sqrtf
#endif

__device__ inline unsigned short f2bf(float f) {  // RNE
  unsigned int u = __float_as_uint(f);
  u = (u + 0x7FFFu + ((u >> 16) & 1u)) >> 16;
  return (unsigned short)u;
}
__device__ inline float bf2f(unsigned short h) {
  return __uint_as_float(((unsigned int)h) << 16);
}
__device__ inline unsigned int pkbf(float lo, float hi) {
  __hip_bfloat162 p = __float22bfloat162_rn(make_float2(lo, hi));
  unsigned int r;
  __builtin_memcpy(&r, &p, 4);
  return r;
}
__device__ inline float mish_f(float x) {
  if (x > 30.f) return x;
  float e = __expf(x);
  float u = 1.f + e;
  float u2 = u * u;
  return x * (u2 - 1.f) / (u2 + 1.f);
}
__device__ inline int swz(int row, int col) {
  return row * DIN + (col ^ ((row & 7) << 3));
}

// Stage a 32x128 bf16 tile into an 8KB LDS region, 64 threads, 8 x 16B each.
// LDS dest LINEAR (rule #21); XOR swizzle applied on the GLOBAL source chunk.
__device__ inline void stage32(const unsigned short* __restrict__ gsrc,
                               unsigned short* region, int tid) {
#pragma unroll
  for (int it = 0; it < 8; ++it) {
    int slot = it * 64 + tid;        // 0..511
    int r = slot >> 4;               // 0..31
    int c8 = (slot & 15) ^ (r & 7);
    __builtin_amdgcn_global_load_lds((const as1u32*)(gsrc + r * DIN + c8 * 8),
                                     (as3u32*)(region + slot * 8), 16, 0, 0);
  }
}

// ---------- wide precompute kernels (unchanged, proven) ----------

__global__ __launch_bounds__(256) void k_pre1(
    const float* __restrict__ W1, const float* __restrict__ W2,
    const float* __restrict__ Wc, const float* __restrict__ Wa,
    const float* __restrict__ mlg,
    unsigned short* W1b, unsigned short* W2b, unsigned short* Wcb,
    float* anc_raw) {
  const int blk = blockIdx.x;
  const int tid = threadIdx.x;
  if (blk < 192) {
    int i = blk * 256 + tid;
    if (i < 16384) {
      W1b[i] = f2bf(W1[i]);
    } else if (i < 32768) {
      W2b[i - 16384] = f2bf(W2[i - 16384]);
    } else {
      int j = i - 32768;
      int o = j >> 10;
      int s = j & 1023;
      Wcb[j] = (o < DOUT) ? f2bf(Wc[o * SSIZE + s]) : (unsigned short)0;
    }
    return;
  }
  int i = (blk - 192) * 256 + tid;
  int s = i >> 7, d = i & 127;
  float acc = 0.f;
  for (int k = 0; k < MLGK; ++k) acc = fmaf(Wa[s * MLGK + k], mlg[k * DIN + d], acc);
  anc_raw[i] = tanhf(acc);
}

__global__ __launch_bounds__(256) void k_pre2(const float* __restrict__ anc_raw,
                                              const float* __restrict__ W1,
                                              const float* __restrict__ b1,
                                              float* anc_h) {
  int i = blockIdx.x * 256 + threadIdx.x;
  int r = i >> 7, d = i & 127;
  float acc = 0.f;
  const float* a = anc_raw + r * DIN;
  const float* w = W1 + d * DIN;
  for (int k = 0; k < DIN; ++k) acc = fmaf(a[k], w[k], acc);
  anc_h[i] = mish_f(acc + b1[d]);
}

__global__ __launch_bounds__(256) void k_pre3(const float* __restrict__ anc_h,
                                              const float* __restrict__ W2,
                                              const float* __restrict__ b2,
                                              unsigned short* ancb, float* a2) {
  __shared__ float part[4];
  const int tid = threadIdx.x;
  const int row = blockIdx.x * 2 + (tid >> 7);
  const int d = tid & 127;
  float acc = 0.f;
  const float* a = anc_h + (size_t)row * DIN;
  const float* w = W2 + d * DIN;
  for (int k = 0; k < DIN; ++k) acc = fmaf(a[k], w[k], acc);
  unsigned short mb = f2bf(mish_f(acc + b2[d]));
  ancb[(size_t)row * DIN + d] = mb;
  float v = bf2f(mb);
  float p = v * v;
  p += __shfl_xor(p, 1);  p += __shfl_xor(p, 2);  p += __shfl_xor(p, 4);
  p += __shfl_xor(p, 8);  p += __shfl_xor(p, 16); p += __shfl_xor(p, 32);
  if ((tid & 63) == 0) part[tid >> 6] = p;
  __syncthreads();
  if (tid == 0)   a2[row]     = part[0] + part[1];
  if (tid == 128) a2[row]     = part[2] + part[3];
}

// ---------- fused main kernel: ONE wave per block, ZERO barriers ----------
// 32 x-rows per wave (2 row-halves) -> ds_read:MFMA = 1:2 in the dist loop.
// All staging synced with counted s_waitcnt vmcnt(N) only (single wave).
// 3-buffer anchor ring staged 2 tiles ahead; a2/Wc reg-prefetch 1 ahead.
// LDS 24 KB -> 6 independent waves/CU. Numerics identical to R12 (0.125).

__global__ __launch_bounds__(64, 2) void k_main(
    const float* __restrict__ x, const float* __restrict__ b1,
    const float* __restrict__ b2, const float* __restrict__ bc,
    const unsigned short* __restrict__ W1b, const unsigned short* __restrict__ W2b,
    const unsigned short* __restrict__ Wcb, const unsigned short* __restrict__ ancb,
    const float* __restrict__ g_a2, float* __restrict__ out) {
  __shared__ __align__(16) unsigned short lds[3 * TM * DIN];  // 3 x 8KB
  unsigned short* p0 = lds;
  unsigned short* p1 = lds + TM * DIN;
  unsigned short* p2 = lds + 2 * TM * DIN;

  const int tid = threadIdx.x;     // == lane, 0..63
  const int l15 = tid & 15;
  const int lhi = tid >> 4;        // 0..3
  const int n0 = blockIdx.x * TM;

  // ---- stage W1 quarter 0; x loads fly underneath ----
  stage32(W1b, p0, tid);

  short8 ah0[4], ah1[4];           // A-fragments: rows l15 / 16+l15
#pragma unroll
  for (int h = 0; h < 2; ++h) {
#pragma unroll
    for (int kk = 0; kk < 4; ++kk) {
      const float* p = x + (size_t)(n0 + h * 16 + l15) * DIN + kk * 32 + lhi * 8;
      float4 u = *(const float4*)p;
      float4 v = *(const float4*)(p + 4);
      pk8 a;
      a.w[0] = pkbf(u.x, u.y);
      a.w[1] = pkbf(u.z, u.w);
      a.w[2] = pkbf(v.x, v.y);
      a.w[3] = pkbf(v.z, v.w);
      if (h == 0) ah0[kk] = a.s8; else ah1[kk] = a.s8;
    }
  }
  stage32(W1b + (size_t)32 * DIN, p1, tid);

  // ---- encode: 2 layers x 4 W-quarters, vmcnt-only pipeline ----
#pragma unroll 1
  for (int qq = 0; qq < 8; ++qq) {
    if (qq == 7) asm volatile("s_waitcnt vmcnt(0)" ::: "memory");
    else         asm volatile("s_waitcnt vmcnt(8)" ::: "memory");
    __builtin_amdgcn_sched_barrier(0);
    unsigned short* wb = (qq & 1) ? p1 : p0;
    if (qq == 4) {  // reload A-fragments from h (p2), before layer-2 overwrites
#pragma unroll
      for (int kk = 0; kk < 4; ++kk) {
        ah0[kk] = *(const short8*)&p2[swz(l15, kk * 32 + lhi * 8)];
        ah1[kk] = *(const short8*)&p2[swz(16 + l15, kk * 32 + lhi * 8)];
      }
    }
    float4v a00 = (float4v){0.f, 0.f, 0.f, 0.f};
    float4v a01 = (float4v){0.f, 0.f, 0.f, 0.f};
    float4v a10 = (float4v){0.f, 0.f, 0.f, 0.f};
    float4v a11 = (float4v){0.f, 0.f, 0.f, 0.f};
#pragma unroll
    for (int kk = 0; kk < 4; ++kk) {
      int k = kk * 32 + lhi * 8;
      short8 w0 = *(const short8*)&wb[swz(l15, k)];        // W cols q*32+0..15
      short8 w1 = *(const short8*)&wb[swz(16 + l15, k)];   // W cols q*32+16..31
      a00 = __builtin_amdgcn_mfma_f32_16x16x32_bf16(ah0[kk], w0, a00, 0, 0, 0);
      a10 = __builtin_amdgcn_mfma_f32_16x16x32_bf16(ah0[kk], w1, a10, 0, 0, 0);
      a01 = __builtin_amdgcn_mfma_f32_16x16x32_bf16(ah1[kk], w0, a01, 0, 0, 0);
      a11 = __builtin_amdgcn_mfma_f32_16x16x32_bf16(ah1[kk], w1, a11, 0, 0, 0);
    }
    __builtin_amdgcn_sched_barrier(0);
    if (qq < 6) {  // stage q(qq+2) into the buffer just consumed
      int qn = qq + 2;
      const unsigned short* Wn = (qn < 4) ? W1b + (size_t)(qn * 32) * DIN
                                          : W2b + (size_t)((qn & 3) * 32) * DIN;
      stage32(Wn, wb, tid);
    }
    const float* bias = (qq < 4) ? b1 : b2;
    const int q = qq & 3;
#pragma unroll
    for (int h = 0; h < 2; ++h) {
#pragma unroll
      for (int ct = 0; ct < 2; ++ct) {
        float4v accv = (h == 0) ? (ct ? a10 : a00) : (ct ? a11 : a01);
        int col = q * 32 + ct * 16 + l15;
        float bv = bias[col];
        float m0 = mish_f(accv[0] + bv);
        float m1 = mish_f(accv[1] + bv);
        float m2 = mish_f(accv[2] + bv);
        float m3 = mish_f(accv[3] + bv);
        unsigned int w01 = pkbf(m0, m1);
        unsigned int w23 = pkbf(m2, m3);
        int r0 = h * 16 + lhi * 4;
        p2[swz(r0 + 0, col)] = (unsigned short)(w01 & 0xffff);
        p2[swz(r0 + 1, col)] = (unsigned short)(w01 >> 16);
        p2[swz(r0 + 2, col)] = (unsigned short)(w23 & 0xffff);
        p2[swz(r0 + 3, col)] = (unsigned short)(w23 >> 16);
      }
    }
  }

  // ---- hoist x_dml B-fragments (both halves) + row norms ----
  short8 bx0[4], bx1[4];
#pragma unroll
  for (int kk = 0; kk < 4; ++kk) {
    bx0[kk] = *(const short8*)&p2[swz(l15, kk * 32 + lhi * 8)];
    bx1[kk] = *(const short8*)&p2[swz(16 + l15, kk * 32 + lhi * 8)];
  }
  float x2v0 = 0.f, x2v1 = 0.f;
#pragma unroll
  for (int kk = 0; kk < 4; ++kk)
#pragma unroll
    for (int e = 0; e < 8; ++e) {
      float v0 = bf2f((unsigned short)bx0[kk][e]);
      float v1 = bf2f((unsigned short)bx1[kk][e]);
      x2v0 = fmaf(v0, v0, x2v0);
      x2v1 = fmaf(v1, v1, x2v1);
    }
  x2v0 += __shfl_xor(x2v0, 16); x2v0 += __shfl_xor(x2v0, 32);
  x2v1 += __shfl_xor(x2v1, 16); x2v1 += __shfl_xor(x2v1, 32);
  __builtin_amdgcn_sched_barrier(0);

  // ---- dist prologue: a0, pf0, a1, a2 (order fixed for vmcnt(24) math) ----
  const unsigned short* wcrow = Wcb + l15 * SSIZE;
  stage32(ancb, p0, tid);                               // a0 [8vm]
  float4 av0 = *(const float4*)(g_a2 + lhi * 4);        // pf0 [4vm]
  float4 av1 = *(const float4*)(g_a2 + 16 + lhi * 4);
  uint2 wv0 = *(const uint2*)(wcrow + lhi * 4);
  uint2 wv1 = *(const uint2*)(wcrow + 16 + lhi * 4);
  stage32(ancb + (size_t)TS * DIN, p1, tid);            // a1 [8vm]
  stage32(ancb + (size_t)2 * TS * DIN, p2, tid);        // a2 [8vm]

  float4v lacc0 = (float4v){0.f, 0.f, 0.f, 0.f};
  float4v lacc1 = (float4v){0.f, 0.f, 0.f, 0.f};
  unsigned short* cur = p0;
  unsigned short* nx1 = p1;
  unsigned short* nx2 = p2;

#pragma unroll 1
  for (int t = 0; t < NT; ++t) {
    // pf(t+1): 4 vm (masked tail keeps counts uniform)
    const int tn = (t + 1) & (NT - 1);
    const float* a2n = g_a2 + tn * TS + lhi * 4;
    const unsigned short* wcn = wcrow + tn * TS + lhi * 4;
    float4 an0 = *(const float4*)(a2n + 0);
    float4 an1 = *(const float4*)(a2n + 16);
    uint2 wn0 = *(const uint2*)(wcn + 0);
    uint2 wn1 = *(const uint2*)(wcn + 16);
    // newest-24 = pf(t+1)4 + a(t+2)8 + pf(t)4 + a(t+1)8 -> a(t) landed
    asm volatile("s_waitcnt vmcnt(24)" ::: "memory");
    __builtin_amdgcn_sched_barrier(0);

    float4v a00 = (float4v){0.f, 0.f, 0.f, 0.f};   // [ct][half]
    float4v a01 = (float4v){0.f, 0.f, 0.f, 0.f};
    float4v a10 = (float4v){0.f, 0.f, 0.f, 0.f};
    float4v a11 = (float4v){0.f, 0.f, 0.f, 0.f};
    __builtin_amdgcn_s_setprio(1);
#pragma unroll
    for (int kk = 0; kk < 4; ++kk) {
      int k = kk * 32 + lhi * 8;
      short8 f0 = *(const short8*)&cur[swz(l15, k)];       // anchors ct0
      short8 f1 = *(const short8*)&cur[swz(16 + l15, k)];  // anchors ct1
      a00 = __builtin_amdgcn_mfma_f32_16x16x32_bf16(f0, bx0[kk], a00, 0, 0, 0);
      a01 = __builtin_amdgcn_mfma_f32_16x16x32_bf16(f0, bx1[kk], a01, 0, 0, 0);
      a10 = __builtin_amdgcn_mfma_f32_16x16x32_bf16(f1, bx0[kk], a10, 0, 0, 0);
      a11 = __builtin_amdgcn_mfma_f32_16x16x32_bf16(f1, bx1[kk], a11, 0, 0, 0);
    }
    __builtin_amdgcn_s_setprio(0);
    // epilogue half 0 (rows l15): ct0 -> k-slots 0-3, ct1 -> 4-7
    {
      pk8 A, B;
      float d0 = fsqrt_fast(fmaxf(fmaf(-2.f, a00[0], x2v0 + av0.x), 0.f));
      float d1 = fsqrt_fast(fmaxf(fmaf(-2.f, a00[1], x2v0 + av0.y), 0.f));
      float d2 = fsqrt_fast(fmaxf(fmaf(-2.f, a00[2], x2v0 + av0.z), 0.f));
      float d3 = fsqrt_fast(fmaxf(fmaf(-2.f, a00[3], x2v0 + av0.w), 0.f));
      A.w[0] = wv0.x; A.w[1] = wv0.y;
      B.w[0] = pkbf(d0, d1); B.w[1] = pkbf(d2, d3);
      float e0 = fsqrt_fast(fmaxf(fmaf(-2.f, a10[0], x2v0 + av1.x), 0.f));
      float e1 = fsqrt_fast(fmaxf(fmaf(-2.f, a10[1], x2v0 + av1.y), 0.f));
      float e2 = fsqrt_fast(fmaxf(fmaf(-2.f, a10[2], x2v0 + av1.z), 0.f));
      float e3 = fsqrt_fast(fmaxf(fmaf(-2.f, a10[3], x2v0 + av1.w), 0.f));
      A.w[2] = wv1.x; A.w[3] = wv1.y;
      B.w[2] = pkbf(e0, e1); B.w[3] = pkbf(e2, e3);
      lacc0 = __builtin_amdgcn_mfma_f32_16x16x32_bf16(A.s8, B.s8, lacc0, 0, 0, 0);
    }
    // epilogue half 1 (rows 16+l15)
    {
      pk8 A, B;
      float d0 = fsqrt_fast(fmaxf(fmaf(-2.f, a01[0], x2v1 + av0.x), 0.f));
      float d1 = fsqrt_fast(fmaxf(fmaf(-2.f, a01[1], x2v1 + av0.y), 0.f));
      float d2 = fsqrt_fast(fmaxf(fmaf(-2.f, a01[2], x2v1 + av0.z), 0.f));
      float d3 = fsqrt_fast(fmaxf(fmaf(-2.f, a01[3], x2v1 + av0.w), 0.f));
      A.w[0] = wv0.x; A.w[1] = wv0.y;
      B.w[0] = pkbf(d0, d1); B.w[1] = pkbf(d2, d3);
      float e0 = fsqrt_fast(fmaxf(fmaf(-2.f, a11[0], x2v1 + av1.x), 0.f));
      float e1 = fsqrt_fast(fmaxf(fmaf(-2.f, a11[1], x2v1 + av1.y), 0.f));
      float e2 = fsqrt_fast(fmaxf(fmaf(-2.f, a11[2], x2v1 + av1.z), 0.f));
      float e3 = fsqrt_fast(fmaxf(fmaf(-2.f, a11[3], x2v1 + av1.w), 0.f));
      A.w[2] = wv1.x; A.w[3] = wv1.y;
      B.w[2] = pkbf(e0, e1); B.w[3] = pkbf(e2, e3);
      lacc1 = __builtin_amdgcn_mfma_f32_16x16x32_bf16(A.s8, B.s8, lacc1, 0, 0, 0);
    }
    __builtin_amdgcn_sched_barrier(0);
    // stage a(t+3) into the buffer just consumed (masked tail; after reads)
    const int t3 = (t + 3) & (NT - 1);
    stage32(ancb + (size_t)t3 * TS * DIN, cur, tid);
    // rotate ring + prefetched scalars
    unsigned short* tmp = cur; cur = nx1; nx1 = nx2; nx2 = tmp;
    av0 = an0; av1 = an1; wv0 = wn0; wv1 = wn1;
  }

  // ---- bias + log_softmax + store, per row-half ----
#pragma unroll
  for (int h = 0; h < 2; ++h) {
    float4v L = h ? lacc1 : lacc0;
    const int xrow = n0 + h * 16 + l15;
    float v[4];
    float m4 = -1e30f;
#pragma unroll
    for (int j = 0; j < 4; ++j) {
      int o = lhi * 4 + j;
      v[j] = (o < DOUT) ? (L[j] + bc[o]) : -1e30f;
      m4 = fmaxf(m4, v[j]);
    }
    m4 = fmaxf(m4, __shfl_xor(m4, 16));
    m4 = fmaxf(m4, __shfl_xor(m4, 32));
    float es = 0.f;
#pragma unroll
    for (int j = 0; j < 4; ++j) {
      int o = lhi * 4 + j;
      es += (o < DOUT) ? __expf(v[j] - m4) : 0.f;
    }
    es += __shfl_xor(es, 16);
    es += __shfl_xor(es, 32);
    float ls = logf(es);
#pragma unroll
    for (int j = 0; j < 4; ++j) {
      int o = lhi * 4 + j;
      if (o < DOUT) out[(size_t)xrow * DOUT + o] = v[j] - m4 - ls;
    }
  }
}

extern "C" void kernel_launch(void* const* d_in, const int* in_sizes, int n_in,
                              void* d_out, int out_size, void* d_ws, size_t ws_size,
                              hipStream_t stream) {
  const float* x   = (const float*)d_in[0];
  const float* mlg = (const float*)d_in[1];
  const float* W1  = (const float*)d_in[2];
  const float* b1  = (const float*)d_in[3];
  const float* W2  = (const float*)d_in[4];
  const float* b2  = (const float*)d_in[5];
  const float* Wa  = (const float*)d_in[6];
  const float* Wc  = (const float*)d_in[7];
  const float* bc  = (const float*)d_in[8];
  float* out = (float*)d_out;

  unsigned short* W1b  = (unsigned short*)d_ws;        // 16384 bf16
  unsigned short* W2b  = W1b + 16384;                  // 16384 bf16
  unsigned short* Wcb  = W2b + 16384;                  // 16*1024 bf16 (zero-padded)
  unsigned short* ancb = Wcb + 16384;                  // 1024*128 bf16
  float* a2      = (float*)(ancb + SSIZE * DIN);       // 1024 f32
  float* anc_raw = a2 + SSIZE;                         // 1024*128 f32
  float* anc_h   = anc_raw + SSIZE * DIN;              // 1024*128 f32

  k_pre1<<<704, 256, 0, stream>>>(W1, W2, Wc, Wa, mlg, W1b, W2b, Wcb, anc_raw);
  k_pre2<<<512, 256, 0, stream>>>(anc_raw, W1, b1, anc_h);
  k_pre3<<<512, 256, 0, stream>>>(anc_h, W2, b2, ancb, a2);
  k_main<<<2048, 64, 0, stream>>>(x, b1, b2, bc, W1b, W2b, Wcb, ancb, a2, out);
}

// Round 15
// 102.860 us; speedup vs baseline: 1.2696x; 1.2696x over previous
//
#include <hip/hip_runtime.h>
#include <hip/hip_bf16.h>

typedef __attribute__((ext_vector_type(8))) short short8;
typedef __attribute__((ext_vector_type(4))) float float4v;
typedef __attribute__((address_space(3))) unsigned int as3u32;
typedef __attribute__((address_space(1))) unsigned int as1u32;

#define DIN 128
#define SSIZE 1024
#define MLGK 256
#define DOUT 10
#define TM 32   // x-rows per block; 2 waves x 16 rows
#define TS 32   // anchors per staged tile
#define NT 32   // anchor tiles
#define NTHR 128

union pk8 { unsigned int w[4]; short8 s8; };

#if __has_builtin(__builtin_amdgcn_sqrtf)
#define fsqrt_fast __builtin_amdgcn_sqrtf
#else
#define fsqrt_fast sqrtf
#endif

__device__ inline unsigned short f2bf(float f) {  // RNE
  unsigned int u = __float_as_uint(f);
  u = (u + 0x7FFFu + ((u >> 16) & 1u)) >> 16;
  return (unsigned short)u;
}
__device__ inline float bf2f(unsigned short h) {
  return __uint_as_float(((unsigned int)h) << 16);
}
// packed RNE f32->bf16 (header path; numerically identical to f2bf)
__device__ inline unsigned int pkbf(float lo, float hi) {
  __hip_bfloat162 p = __float22bfloat162_rn(make_float2(lo, hi));
  unsigned int r;
  __builtin_memcpy(&r, &p, 4);
  return r;
}
__device__ inline float mish_f(float x) {
  if (x > 30.f) return x;
  float e = __expf(x);
  float u = 1.f + e;
  float u2 = u * u;
  return x * (u2 - 1.f) / (u2 + 1.f);
}
// element-index XOR swizzle; identical to the chunk-XOR used by stage8k
__device__ inline int swz(int row, int col) {
  return row * DIN + (col ^ ((row & 7) << 3));
}

// Stage a 32x128 bf16 tile (row stride DIN) into an 8KB LDS region via
// global_load_lds width=16, 128 threads. LDS dest LINEAR (rule #21); XOR
// swizzle applied by permuting the GLOBAL source chunk.
__device__ inline void stage8k(const unsigned short* __restrict__ gsrc,
                               unsigned short* region, int tid) {
#pragma unroll
  for (int it = 0; it < 4; ++it) {
    int slot = it * NTHR + tid;      // 0..511
    int r = slot >> 4;               // 0..31
    int c8 = (slot & 15) ^ (r & 7);
    __builtin_amdgcn_global_load_lds((const as1u32*)(gsrc + r * DIN + c8 * 8),
                                     (as3u32*)(region + slot * 8), 16, 0, 0);
  }
}

// ---------- single fused precompute kernel ----------
// blocks 0..191: weights -> bf16 (W1b, W2b, zero-padded Wcb). Exact prior code.
// blocks 192..319: anchor pipeline, 8 anchors/block, f32 math, all operand
// reads either coalesced-staged into LDS (W chunks) or LDS-broadcast (AR/OUT).
// fmaf order ascending-k everywhere => anchors/a2 bit-identical to the old
// k_pre1/2/3 chain (absmax stays exactly 0.125).

__global__ __launch_bounds__(256) void k_pre(
    const float* __restrict__ W1, const float* __restrict__ W2,
    const float* __restrict__ Wc, const float* __restrict__ Wa,
    const float* __restrict__ mlg, const float* __restrict__ b1,
    const float* __restrict__ b2,
    unsigned short* W1b, unsigned short* W2b, unsigned short* Wcb,
    unsigned short* ancb, float* a2) {
  const int blk = blockIdx.x;
  const int tid = threadIdx.x;
  if (blk < 192) {
    int i = blk * 256 + tid;  // 49152 total
    if (i < 16384) {
      W1b[i] = f2bf(W1[i]);
    } else if (i < 32768) {
      W2b[i - 16384] = f2bf(W2[i - 16384]);
    } else {
      int j = i - 32768;  // [16][1024] padded Wc (rows >= DOUT zero)
      int o = j >> 10;
      int s = j & 1023;
      Wcb[j] = (o < DOUT) ? f2bf(Wc[o * SSIZE + s]) : (unsigned short)0;
    }
    return;
  }
  // ---- anchor blocks: 128 blocks x 8 anchors ----
  __shared__ __align__(16) float AR[8][132];   // tanh output (padded rows)
  __shared__ __align__(16) float OUT[8][132];  // layer-1 mish output
  __shared__ __align__(16) float WC[32][132];  // staged W chunk (32 rows)
  const int s0 = (blk - 192) * 8;

  // phase 1: AR = tanh(Wa @ mlg); thread (d, sg) does 4 anchors' col d
  {
    const int d = tid & 127;
    const int sg = tid >> 7;  // 0/1 -> anchors sg*4 .. sg*4+3
    float ac0 = 0.f, ac1 = 0.f, ac2 = 0.f, ac3 = 0.f;
    const float* wr = Wa + (size_t)(s0 + sg * 4) * MLGK;
    for (int k = 0; k < MLGK; ++k) {
      float m = mlg[k * DIN + d];
      ac0 = fmaf(wr[0 * MLGK + k], m, ac0);
      ac1 = fmaf(wr[1 * MLGK + k], m, ac1);
      ac2 = fmaf(wr[2 * MLGK + k], m, ac2);
      ac3 = fmaf(wr[3 * MLGK + k], m, ac3);
    }
    AR[sg * 4 + 0][d] = tanhf(ac0);
    AR[sg * 4 + 1][d] = tanhf(ac1);
    AR[sg * 4 + 2][d] = tanhf(ac2);
    AR[sg * 4 + 3][d] = tanhf(ac3);
  }
  __syncthreads();

  // phases 2/3: LDS GEMM per 32-col chunk; thread (a = tid>>5, c = tid&31)
  const int a = tid >> 5;   // 0..7
  const int c = tid & 31;   // 0..31
  float sqacc = 0.f;
#pragma unroll 1
  for (int layer = 0; layer < 2; ++layer) {
    const float* W = layer ? W2 : W1;
    const float* bias = layer ? b2 : b1;
#pragma unroll 1
    for (int ch = 0; ch < 4; ++ch) {
      // stage W rows ch*32..+31 (full K), coalesced float4 copies
      for (int i = tid; i < 32 * 32; i += 256) {
        int cr = i >> 5;
        int g = i & 31;
        float4 v = *(const float4*)&W[(size_t)(ch * 32 + cr) * DIN + g * 4];
        *(float4*)&WC[cr][g * 4] = v;
      }
      __syncthreads();
      float acc = 0.f;
      const float* src = layer ? &OUT[a][0] : &AR[a][0];
#pragma unroll
      for (int g = 0; g < 32; ++g) {
        float4 av = *(const float4*)&src[g * 4];     // LDS broadcast per a
        float4 wv = *(const float4*)&WC[c][g * 4];   // padded rows, ~4-way
        acc = fmaf(av.x, wv.x, acc);
        acc = fmaf(av.y, wv.y, acc);
        acc = fmaf(av.z, wv.z, acc);
        acc = fmaf(av.w, wv.w, acc);
      }
      int col = ch * 32 + c;
      float m = mish_f(acc + bias[col]);
      if (layer == 0) {
        OUT[a][col] = m;
      } else {
        unsigned short mb = f2bf(m);
        ancb[(size_t)(s0 + a) * DIN + col] = mb;
        float v = bf2f(mb);
        sqacc = fmaf(v, v, sqacc);
      }
      __syncthreads();  // all reads done before next chunk overwrites WC
    }
  }
  // a2: reduce sqacc over the 32 lanes sharing anchor a
  sqacc += __shfl_xor(sqacc, 1);
  sqacc += __shfl_xor(sqacc, 2);
  sqacc += __shfl_xor(sqacc, 4);
  sqacc += __shfl_xor(sqacc, 8);
  sqacc += __shfl_xor(sqacc, 16);
  if (c == 0) a2[s0 + a] = sqacc;
}

// ---------- fused main kernel (R12 EXACT — proven 82-85 us, absmax 0.125) ----------
// TM=32: 128 threads, 2 waves x 16 rows, grid 2048, LDS 16 KB -> 8 blocks/CU.

__global__ __launch_bounds__(NTHR, 8) void k_main(
    const float* __restrict__ x, const float* __restrict__ b1,
    const float* __restrict__ b2, const float* __restrict__ bc,
    const unsigned short* __restrict__ W1b, const unsigned short* __restrict__ W2b,
    const unsigned short* __restrict__ Wcb, const unsigned short* __restrict__ ancb,
    const float* __restrict__ a2, float* __restrict__ out) {
  __shared__ __align__(16) unsigned short reg0[TM * DIN];  // h/x_dml; anchor buf A
  __shared__ __align__(16) unsigned short reg1[TM * DIN];  // W quarters; anchor buf B

  const int tid = threadIdx.x;
  const int lane = tid & 63;
  const int l15 = lane & 15;
  const int lhi = lane >> 4;
  const int n0 = blockIdx.x * TM;
  const int rbase = (tid >> 6) * 16;   // wave 0 -> rows 0-15, wave 1 -> 16-31

  // issue first W quarter stage immediately; x loads fly underneath
  stage8k(W1b, reg1, tid);

  // ---- x rows -> bf16 A-fragments (global -> reg) ----
  short8 af[4];
#pragma unroll
  for (int kk = 0; kk < 4; ++kk) {
    const float* p = x + (size_t)(n0 + rbase + l15) * DIN + kk * 32 + lhi * 8;
    float4 u = *(const float4*)p;
    float4 v = *(const float4*)(p + 4);
    pk8 a;
    a.w[0] = pkbf(u.x, u.y);
    a.w[1] = pkbf(u.z, u.w);
    a.w[2] = pkbf(v.x, v.y);
    a.w[3] = pkbf(v.z, v.w);
    af[kk] = a.s8;
  }

  // ---- encode: 2 layers x 4 staged 32-col quarters of W ----
  short8 ah[4];
#pragma unroll
  for (int kk = 0; kk < 4; ++kk) ah[kk] = af[kk];
#pragma unroll 1
  for (int qq = 0; qq < 8; ++qq) {
    const int layer = qq >> 2;
    const int q = qq & 3;
    const float* bias = layer ? b2 : b1;
    if (q == 0 && layer == 1) {
#pragma unroll
      for (int kk = 0; kk < 4; ++kk)
        ah[kk] = *(const short8*)&reg0[swz(rbase + l15, kk * 32 + lhi * 8)];
    }
    __syncthreads();  // quarter qq staged (vmcnt drained by barrier)
    float4v acc0 = (float4v){0.f, 0.f, 0.f, 0.f};
    float4v acc1 = (float4v){0.f, 0.f, 0.f, 0.f};
#pragma unroll
    for (int kk = 0; kk < 4; ++kk) {
      int k = kk * 32 + lhi * 8;
      short8 bA = *(const short8*)&reg1[swz(l15, k)];
      short8 bB = *(const short8*)&reg1[swz(16 + l15, k)];
      acc0 = __builtin_amdgcn_mfma_f32_16x16x32_bf16(ah[kk], bA, acc0, 0, 0, 0);
      acc1 = __builtin_amdgcn_mfma_f32_16x16x32_bf16(ah[kk], bB, acc1, 0, 0, 0);
    }
    __syncthreads();  // all waves done reading reg1
    if (qq < 7) {
      const unsigned short* Wn = (qq + 1 < 4) ? W1b + (size_t)((qq + 1) * 32) * DIN
                                              : W2b + (size_t)(((qq + 1) & 3) * 32) * DIN;
      stage8k(Wn, reg1, tid);
    }
#pragma unroll
    for (int ct = 0; ct < 2; ++ct) {
      float4v accv = ct ? acc1 : acc0;
      int col = q * 32 + ct * 16 + l15;
      float bv = bias[col];
      float m0 = mish_f(accv[0] + bv);
      float m1 = mish_f(accv[1] + bv);
      float m2 = mish_f(accv[2] + bv);
      float m3 = mish_f(accv[3] + bv);
      unsigned int w01 = pkbf(m0, m1);
      unsigned int w23 = pkbf(m2, m3);
      int r0 = rbase + lhi * 4;
      reg0[swz(r0 + 0, col)] = (unsigned short)(w01 & 0xffff);
      reg0[swz(r0 + 1, col)] = (unsigned short)(w01 >> 16);
      reg0[swz(r0 + 2, col)] = (unsigned short)(w23 & 0xffff);
      reg0[swz(r0 + 3, col)] = (unsigned short)(w23 >> 16);
    }
  }

  // ---- hoist x_dml B-fragments; row norm from the rounded registers ----
  short8 bx[4];
#pragma unroll
  for (int kk = 0; kk < 4; ++kk)
    bx[kk] = *(const short8*)&reg0[swz(rbase + l15, kk * 32 + lhi * 8)];
  float x2v = 0.f;
#pragma unroll
  for (int kk = 0; kk < 4; ++kk)
#pragma unroll
    for (int e = 0; e < 8; ++e) {
      float v = bf2f((unsigned short)bx[kk][e]);
      x2v = fmaf(v, v, x2v);
    }
  x2v += __shfl_xor(x2v, 16);
  x2v += __shfl_xor(x2v, 32);   // full row-norm of row rbase+l15

  // ---- prefetch tile 0's a2 / Wc (named scalars) ----
  const unsigned short* wcrow = Wcb + l15 * SSIZE;
  float4 av0 = *(const float4*)(a2 + lhi * 4);
  float4 av1 = *(const float4*)(a2 + 16 + lhi * 4);
  uint2 wv0 = *(const uint2*)(wcrow + lhi * 4);
  uint2 wv1 = *(const uint2*)(wcrow + 16 + lhi * 4);
  __syncthreads();              // everyone done with reg0 before anchor staging

  // ---- distance + in-register logits over 32 anchor tiles of 32 ----
  float4v lacc = (float4v){0.f, 0.f, 0.f, 0.f};

  auto dist_tile = [&](const unsigned short* buf, int t) {
    int tn = (t + 1) & (NT - 1);
    const float* a2n = a2 + tn * TS + lhi * 4;
    const unsigned short* wcn = wcrow + tn * TS + lhi * 4;
    float4 an0 = *(const float4*)(a2n + 0);
    float4 an1 = *(const float4*)(a2n + 16);
    uint2 wn0 = *(const uint2*)(wcn + 0);
    uint2 wn1 = *(const uint2*)(wcn + 16);

    float4v acc0 = (float4v){0.f, 0.f, 0.f, 0.f};
    float4v acc1 = (float4v){0.f, 0.f, 0.f, 0.f};
    __builtin_amdgcn_s_setprio(1);
#pragma unroll
    for (int kk = 0; kk < 4; ++kk) {
      int k = kk * 32 + lhi * 8;
      short8 aA = *(const short8*)&buf[swz(l15, k)];
      short8 aB = *(const short8*)&buf[swz(16 + l15, k)];
      acc0 = __builtin_amdgcn_mfma_f32_16x16x32_bf16(aA, bx[kk], acc0, 0, 0, 0);
      acc1 = __builtin_amdgcn_mfma_f32_16x16x32_bf16(aB, bx[kk], acc1, 0, 0, 0);
    }
    __builtin_amdgcn_s_setprio(0);
    {
      pk8 A, B;
      float d0 = fsqrt_fast(fmaxf(fmaf(-2.f, acc0[0], x2v + av0.x), 0.f));
      float d1 = fsqrt_fast(fmaxf(fmaf(-2.f, acc0[1], x2v + av0.y), 0.f));
      float d2 = fsqrt_fast(fmaxf(fmaf(-2.f, acc0[2], x2v + av0.z), 0.f));
      float d3 = fsqrt_fast(fmaxf(fmaf(-2.f, acc0[3], x2v + av0.w), 0.f));
      A.w[0] = wv0.x; A.w[1] = wv0.y;
      B.w[0] = pkbf(d0, d1); B.w[1] = pkbf(d2, d3);
      float e0 = fsqrt_fast(fmaxf(fmaf(-2.f, acc1[0], x2v + av1.x), 0.f));
      float e1 = fsqrt_fast(fmaxf(fmaf(-2.f, acc1[1], x2v + av1.y), 0.f));
      float e2 = fsqrt_fast(fmaxf(fmaf(-2.f, acc1[2], x2v + av1.z), 0.f));
      float e3 = fsqrt_fast(fmaxf(fmaf(-2.f, acc1[3], x2v + av1.w), 0.f));
      A.w[2] = wv1.x; A.w[3] = wv1.y;
      B.w[2] = pkbf(e0, e1); B.w[3] = pkbf(e2, e3);
      lacc = __builtin_amdgcn_mfma_f32_16x16x32_bf16(A.s8, B.s8, lacc, 0, 0, 0);
    }
    av0 = an0; av1 = an1; wv0 = wn0; wv1 = wn1;
  };

  stage8k(ancb, reg0, tid);  // tile 0
  __syncthreads();
#pragma unroll 1
  for (int tp = 0; tp < NT / 2; ++tp) {
    stage8k(ancb + (size_t)(2 * tp + 1) * TS * DIN, reg1, tid);
    dist_tile(reg0, 2 * tp);
    __syncthreads();
    if (tp < NT / 2 - 1)
      stage8k(ancb + (size_t)(2 * tp + 2) * TS * DIN, reg0, tid);
    dist_tile(reg1, 2 * tp + 1);
    __syncthreads();
  }
  float4v L = lacc;

  // ---- bias + log_softmax + store (lane holds logits[lhi*4+j][row l15]) ----
  {
    const int xrow = n0 + rbase + l15;
    float v[4];
    float m4 = -1e30f;
#pragma unroll
    for (int j = 0; j < 4; ++j) {
      int o = lhi * 4 + j;
      v[j] = (o < DOUT) ? (L[j] + bc[o]) : -1e30f;
      m4 = fmaxf(m4, v[j]);
    }
    m4 = fmaxf(m4, __shfl_xor(m4, 16));
    m4 = fmaxf(m4, __shfl_xor(m4, 32));
    float es = 0.f;
#pragma unroll
    for (int j = 0; j < 4; ++j) {
      int o = lhi * 4 + j;
      es += (o < DOUT) ? __expf(v[j] - m4) : 0.f;
    }
    es += __shfl_xor(es, 16);
    es += __shfl_xor(es, 32);
    float ls = logf(es);
#pragma unroll
    for (int j = 0; j < 4; ++j) {
      int o = lhi * 4 + j;
      if (o < DOUT) out[(size_t)xrow * DOUT + o] = v[j] - m4 - ls;
    }
  }
}

extern "C" void kernel_launch(void* const* d_in, const int* in_sizes, int n_in,
                              void* d_out, int out_size, void* d_ws, size_t ws_size,
                              hipStream_t stream) {
  const float* x   = (const float*)d_in[0];
  const float* mlg = (const float*)d_in[1];
  const float* W1  = (const float*)d_in[2];
  const float* b1  = (const float*)d_in[3];
  const float* W2  = (const float*)d_in[4];
  const float* b2  = (const float*)d_in[5];
  const float* Wa  = (const float*)d_in[6];
  const float* Wc  = (const float*)d_in[7];
  const float* bc  = (const float*)d_in[8];
  float* out = (float*)d_out;

  // workspace layout (~0.36 MB)
  unsigned short* W1b  = (unsigned short*)d_ws;        // 16384 bf16
  unsigned short* W2b  = W1b + 16384;                  // 16384 bf16
  unsigned short* Wcb  = W2b + 16384;                  // 16*1024 bf16 (zero-padded)
  unsigned short* ancb = Wcb + 16384;                  // 1024*128 bf16
  float* a2 = (float*)(ancb + SSIZE * DIN);            // 1024 f32

  k_pre<<<320, 256, 0, stream>>>(W1, W2, Wc, Wa, mlg, b1, b2,
                                 W1b, W2b, Wcb, ancb, a2);
  k_main<<<2048, NTHR, 0, stream>>>(x, b1, b2, bc, W1b, W2b, Wcb, ancb, a2, out);
}